// Round 7
// baseline (3306.230 us; speedup 1.0000x reference)
//
#include <hip/hip_runtime.h>
#include <hip/hip_cooperative_groups.h>

namespace cg = cooperative_groups;

// H=W=1024, T=16, 20 iterations.
//
// R12 = R11 inner loop (pair-buffer, single-f4-gather, exact zero-skip)
//       restructured as ONE persistent cooperative kernel:
//  - 1024 blocks x 256 thr, __launch_bounds__(256,4) -> 4 blocks/CU
//    co-resident (cooperative launch validates this).
//  - per iteration: blocks pop 16x16 tiles from an atomic ticket counter over
//    a heavy-first tile order (counting sort by active-transform count) ->
//    no dispatch tail from load imbalance; then grid.sync().
//  - removes 19 inter-dispatch gaps + per-dispatch ramp/tail.
//  - fallback: if hipLaunchCooperativeKernel errors, enqueue the proven
//    20-dispatch path.
//
// Intermediates live in two VERTICAL-PAIR buffers:
//   buf2[r][c] = ( pad[r-1][c-1], pad[r][c-1] )   (float2, 8 B)
// where pad[y][x] is the zero-bordered padded canvas (pixel (h,w) at
// pad[h+1][w+1]). The 4 bilinear corners of a sample live in TWO ADJACENT f2
// elements -> ONE 16B dwordx4 gather per (pixel, transform). Guards/gutters
// are memset-zero once and never written, so clamped OOB samples read exact
// 0.0 (zeros padding exact).
constexpr int W = 1024;
constexpr int H = 1024;
constexpr int T = 16;
constexpr int ITERS = 20;
constexpr int P2 = 1040;                 // f2 elements per row (8320 B rows)
constexpr int ROWS2 = 1027;              // rows 0..1026 readable
constexpr int ALLOC2F = ROWS2 * P2 * 2;  // floats per pair-buffer allocation
constexpr int TILES_X = W / 16;          // 64
constexpr int TILES_Y = H / 16;          // 64
constexpr int NTILES = TILES_X * TILES_Y;
constexpr int NBLOCKS = 1024;            // 4 blocks/CU x 256 CUs

typedef float f2 __attribute__((ext_vector_type(2), aligned(8)));
typedef float f4 __attribute__((ext_vector_type(4), aligned(8)));  // 8B-aligned ok

// coef per transform t: {p, Ax, Bx, Cxb, Ay, By, Cyb, 0}; Cxb/Cyb include the
// +1 pad shift AND +1 clamp bias. Also zeroes the per-iteration ticket
// counters (workspace is poisoned before each run).
__global__ void setup_coef(const float* __restrict__ theta,
                           const float* __restrict__ probs,
                           float* __restrict__ coef,
                           int* __restrict__ cnt) {
    int t = threadIdx.x;
    if (t >= 32 && t - 32 < ITERS) cnt[t - 32] = 0;
    if (t >= T) return;
    float sum = 0.f;
    for (int i = 0; i < T; ++i) sum += probs[i];
    float p = probs[t] / sum;
    const float* th = theta + 6 * t;
    float a = th[0], b = th[1], c = th[2];
    float d = th[3], e = th[4], f = th[5];
    float Cx = a * ((1.0f - (float)W) * 0.5f)
             + b * ((1.0f - (float)H) * 0.5f)
             + (c + 1.0f) * ((float)W * 0.5f) - 0.5f;
    float Cy = d * ((1.0f - (float)W) * 0.5f)
             + e * ((1.0f - (float)H) * 0.5f)
             + (f + 1.0f) * ((float)H * 0.5f) - 0.5f;
    float* o = coef + 8 * t;
    o[0] = p;  o[1] = a;  o[2] = b;  o[3] = Cx + 2.0f;
    o[4] = d;  o[5] = e;  o[6] = Cy + 2.0f; o[7] = 0.f;
}

// One thread per 16x16 tile: conservative bbox hit test (exact skip), compact
// the active transforms' 8-float coef rows, zero-pad count to multiple of 4
// (dummy rows are all-zero -> p=0, off=0 -> exact no-op).
__global__ __launch_bounds__(256) void setup_tiles(const float* __restrict__ coef,
                                                   float* __restrict__ tbl,
                                                   int* __restrict__ tcnt) {
    int tile = blockIdx.x * 256 + threadIdx.x;
    if (tile >= NTILES) return;
    int tx = tile & (TILES_X - 1), ty = tile >> 6;
    float w0 = (float)(tx * 16), w1 = w0 + 15.f;
    float h0 = (float)(ty * 16), h1 = h0 + 15.f;
    float* o = tbl + tile * 128;
    int n = 0;
    for (int t = 0; t < T; ++t) {
        const float* c = coef + t * 8;
        float Ax = c[1], Bx = c[2], Cx = c[3];
        float Ay = c[4], By = c[5], Cy = c[6];
        float xmin = Cx + (Ax >= 0.f ? Ax * w0 : Ax * w1) + (Bx >= 0.f ? Bx * h0 : Bx * h1);
        float xmax = Cx + (Ax >= 0.f ? Ax * w1 : Ax * w0) + (Bx >= 0.f ? Bx * h1 : Bx * h0);
        float ymin = Cy + (Ay >= 0.f ? Ay * w0 : Ay * w1) + (By >= 0.f ? By * h0 : By * h1);
        float ymax = Cy + (Ay >= 0.f ? Ay * w1 : Ay * w0) + (By >= 0.f ? By * h1 : By * h0);
        bool hit = !(xmax <= 1.f || xmin >= (float)(W + 2) ||
                     ymax <= 1.f || ymin >= (float)(H + 2));
        if (hit) {
            for (int j = 0; j < 8; ++j) o[n * 8 + j] = c[j];
            ++n;
        }
    }
    tcnt[tile] = n;
    int np = (n + 3) & ~3;
    for (int s = n; s < np; ++s)
        for (int j = 0; j < 8; ++j) o[s * 8 + j] = 0.f;
}

// Counting sort of tiles by active-transform count, DESCENDING (heavy first).
// Single block; order within a bin is arbitrary (output independent of order).
__global__ __launch_bounds__(256) void sort_tiles(const int* __restrict__ tcnt,
                                                  int* __restrict__ order) {
    __shared__ int hist[T + 1];
    __shared__ int binpos[T + 1];
    int lid = threadIdx.x;
    if (lid <= T) hist[lid] = 0;
    __syncthreads();
    for (int i = lid; i < NTILES; i += 256)
        atomicAdd(&hist[tcnt[i]], 1);
    __syncthreads();
    if (lid == 0) {
        int acc = 0;
        for (int b = T; b >= 0; --b) { binpos[b] = acc; acc += hist[b]; }
    }
    __syncthreads();
    for (int i = lid; i < NTILES; i += 256) {
        int pos = atomicAdd(&binpos[tcnt[i]], 1);
        order[pos] = i;
    }
}

// Build initial pair buffer from canvas0: pixel (h,w) value v contributes
// buf2[h+2][w+2].x = v and buf2[h+1][w+2].y = v. Borders stay memset-zero.
__global__ __launch_bounds__(256) void copy_in(const float* __restrict__ src,
                                               float* __restrict__ dstf) {
    int i = blockIdx.x * 256 + threadIdx.x;   // i in [0, H*W)
    int h = i >> 10, w = i & 1023;
    float v = src[i];
    int c = w + 2;
    dstf[(((h + 2) * P2) + c) * 2 + 0] = v;
    dstf[(((h + 1) * P2) + c) * 2 + 1] = v;
}

// K transforms per group: coefs via uniform scalar loads; one f4 gather per
// transform fetches all 4 corners (v00,v10,v01,v11). Fully-dead wave skips
// the gather (scalar branch); dead lanes collapse to offset 0.
template <int K>
__device__ __forceinline__ void ifs_body(const float* __restrict__ tc, int g,
                                         const f2* __restrict__ gb,
                                         float wf, float hf, float& acc) {
    float fx[K], fy[K], pp[K];
    int off[K];
    unsigned long long lv[K];
#pragma unroll
    for (int k = 0; k < K; ++k) {
        const float* c = tc + (g + k) * 8;          // uniform -> s_load
        float p = c[0], Ax = c[1], Bx = c[2], Cx = c[3];
        float Ay = c[4], By = c[5], Cy = c[6];
        float xb = fmaf(Ax, wf, fmaf(Bx, hf, Cx));
        float yb = fmaf(Ay, wf, fmaf(By, hf, Cy));
        // live <=> contribution can be nonzero
        bool live = (xb > 1.f) & (xb < 1026.f) & (yb > 1.f) & (yb < 1026.f);
        lv[k] = __ballot(live);
        float xc = fminf(fmaxf(xb, 0.f), 1037.f);   // v_med3
        float yc = fminf(fmaxf(yb, 0.f), 1026.f);
        float xi = floorf(xc), yi = floorf(yc);
        fx[k] = xc - xi;
        fy[k] = yc - yi;
        int o = (int)fmaf(yi, (float)P2, xi);       // exact (< 2^24)
        off[k] = live ? o : 0;                      // dead lane -> guard row 0
        pp[k] = p;
    }
    f4 q[K];
#pragma unroll
    for (int k = 0; k < K; ++k) {                   // live gathers in flight
        if (lv[k]) q[k] = *(const f4*)(gb + off[k]);
        else       q[k] = f4{0.f, 0.f, 0.f, 0.f};   // all corners zero
    }
#pragma unroll
    for (int k = 0; k < K; ++k) {
        // q = (v00, v10, v01, v11)
        float top = fmaf(fx[k], q[k].z - q[k].x, q[k].x);
        float bot = fmaf(fx[k], q[k].w - q[k].y, q[k].y);
        acc = fmaf(pp[k], fmaf(fy[k], bot - top, top), acc);
    }
}

__device__ __forceinline__ void do_tile(int tile, const f2* __restrict__ gb,
                                        float* __restrict__ dstf,
                                        const float* __restrict__ tbl,
                                        const int* __restrict__ tcnt,
                                        float basev, int last) {
    int tx = tile & (TILES_X - 1), ty = tile >> 6;
    const float* tc = tbl + tile * 128;             // uniform
    int np = (tcnt[tile] + 3) & ~3;                 // uniform trip count

    // 8x8-per-wave mapping; 4 waves tile a 16x16 pixel block.
    int lid = threadIdx.x;
    int lane = lid & 63, wv = lid >> 6;
    int w = (tx << 4) + ((wv & 1) << 3) + (lane & 7);
    int h = (ty << 4) + ((wv >> 1) << 3) + (lane >> 3);
    float wf = (float)w, hf = (float)h;

    float acc = 0.f;
    int g = 0;
    for (; g + 8 <= np; g += 8) ifs_body<8>(tc, g, gb, wf, hf, acc);
    if (g < np)                 ifs_body<4>(tc, g, gb, wf, hf, acc);

    if (last) {
        dstf[(h << 10) + w] = acc + basev;
    } else {
        int c = w + 2;
        dstf[(((h + 2) * P2) + c) * 2 + 0] = acc;
        dstf[(((h + 1) * P2) + c) * 2 + 1] = acc;
    }
}

// Persistent cooperative kernel: all 20 iterations, work-stealing per iter.
__global__ __launch_bounds__(256, 4) void ifs_persist(
        float* __restrict__ bufAf, float* __restrict__ bufBf,
        float* __restrict__ outf,
        const float* __restrict__ tbl, const int* __restrict__ tcnt,
        const int* __restrict__ order, int* __restrict__ cnt,
        const float* __restrict__ base) {
    cg::grid_group grid = cg::this_grid();
    __shared__ int s_slot;
    float basev = base[0];

    for (int it = 0; it < ITERS; ++it) {
        const f2* gb = (const f2*)((it & 1) ? bufBf : bufAf);
        int last = (it == ITERS - 1) ? 1 : 0;
        float* dstf = last ? outf : ((it & 1) ? bufAf : bufBf);

        for (;;) {
            if (threadIdx.x == 0) s_slot = atomicAdd(cnt + it, 1);
            __syncthreads();
            int slot = s_slot;
            __syncthreads();
            if (slot >= NTILES) break;
            do_tile(order[slot], gb, dstf, tbl, tcnt, basev, last);
        }
        grid.sync();
    }
}

// Legacy per-iteration kernel (fallback if cooperative launch unavailable).
__global__ __launch_bounds__(256) void ifs_iter(const float* __restrict__ inf,
                                                float* __restrict__ dstf,
                                                const float* __restrict__ tbl,
                                                const int* __restrict__ tcnt,
                                                const float* __restrict__ base,
                                                int last) {
    int tile = blockIdx.y * TILES_X + blockIdx.x;
    do_tile(tile, (const f2*)inf, dstf, tbl, tcnt, base[0], last);
}

extern "C" void kernel_launch(void* const* d_in, const int* in_sizes, int n_in,
                              void* d_out, int out_size, void* d_ws, size_t ws_size,
                              hipStream_t stream) {
    const float* canvas0 = (const float*)d_in[0];
    const float* theta   = (const float*)d_in[1];
    const float* probs   = (const float*)d_in[2];
    const float* base    = (const float*)d_in[3];

    float* raw   = (float*)d_ws;
    float* bufAf = raw;
    float* bufBf = raw + ALLOC2F;
    float* coef  = raw + 2 * ALLOC2F;
    float* tbl   = coef + T * 8;
    int*   tcnt  = (int*)(tbl + NTILES * 128);
    int*   order = tcnt + NTILES;
    int*   cnt   = order + NTILES;

    // zero both pair buffers: borders, gutters, guards (and kills poison)
    hipMemsetAsync(raw, 0, (size_t)2 * ALLOC2F * sizeof(float), stream);

    setup_coef<<<1, 64, 0, stream>>>(theta, probs, coef, cnt);
    setup_tiles<<<(NTILES + 255) / 256, 256, 0, stream>>>(coef, tbl, tcnt);
    sort_tiles<<<1, 256, 0, stream>>>(tcnt, order);
    copy_in<<<(H * W) / 256, 256, 0, stream>>>(canvas0, bufAf);

    float* outp = (float*)d_out;
    void* args[] = {&bufAf, &bufBf, &outp, &tbl, &tcnt, &order, &cnt,
                    (void*)&base};
    hipError_t err = hipLaunchCooperativeKernel((const void*)ifs_persist,
                                                dim3(NBLOCKS), dim3(256),
                                                args, 0, stream);
    if (err != hipSuccess) {
        // Fallback: proven 20-dispatch path (bit-identical result).
        dim3 block(256);
        dim3 grid(TILES_X, TILES_Y);
        const float* cur = bufAf;
        for (int i = 0; i < ITERS; ++i) {
            bool last = (i == ITERS - 1);
            float* dst = last ? outp : ((i & 1) ? bufAf : bufBf);
            ifs_iter<<<grid, block, 0, stream>>>(cur, dst, tbl, tcnt, base,
                                                 last ? 1 : 0);
            cur = dst;
        }
    }
}

// Round 8
// 482.977 us; speedup vs baseline: 6.8455x; 6.8455x over previous
//
#include <hip/hip_runtime.h>

// H=W=1024, T=16, 20 iterations.
//
// R13 = R11 (pair-buffer, single-f4-gather, 20 dispatches — R12 coop reverted)
//       + per-transform ADAPTIVE WAVE-PATCH SHAPE:
//   - lines probed per wave-gather depend on the patch's image under A:
//     rows ~ pw|Ay|+ph|By|, bytes/row ~ (pw|Ax|+ph|Bx|)*8. setup_coef picks
//     shape s in {4x16, 8x8, 16x4} minimizing modeled line count.
//   - transforms bucketed by shape (3 groups, each padded to x4 with exact
//     no-op dummies); per group the thread->pixel map is fixed, accumulate in
//     a register, then flush into a 256-float LDS pixel accumulator
//     (sync; lds[pix] += accR; unique owner per pixel -> race-free).
//   - summation order becomes shape-grouped (deterministic); absmax moves to
//     float-reassociation level (~1e-7), well inside tolerance.
//
// Intermediates live in two VERTICAL-PAIR buffers:
//   buf2[r][c] = ( pad[r-1][c-1], pad[r][c-1] )   (float2, 8 B)
// pad[y][x] = zero-bordered padded canvas (pixel (h,w) at pad[h+1][w+1]).
// All 4 bilinear corners of a sample sit in TWO ADJACENT f2 cells -> ONE 16B
// dwordx4 gather per (pixel, transform). Guards/gutters memset-zero once and
// never written -> clamped OOB samples read exact 0.0 (zeros padding exact).
constexpr int W = 1024;
constexpr int H = 1024;
constexpr int T = 16;
constexpr int ITERS = 20;
constexpr int P2 = 1040;                 // f2 elements per row (8320 B rows)
constexpr int ROWS2 = 1027;              // rows 0..1026 readable
constexpr int ALLOC2F = ROWS2 * P2 * 2;  // floats per pair-buffer allocation
constexpr int TILES_X = W / 16;          // 64
constexpr int TILES_Y = H / 16;          // 64
constexpr int NTILES = TILES_X * TILES_Y;
constexpr int TSTR = 256;                // floats per tile table entry

typedef float f2 __attribute__((ext_vector_type(2), aligned(8)));
typedef float f4 __attribute__((ext_vector_type(4), aligned(8)));  // 8B-aligned ok

// coef per transform t: {p, Ax, Bx, Cxb, Ay, By, Cyb, shape}; Cxb/Cyb include
// the +1 pad shift AND +1 clamp bias. shape = int bits s in {2,3,4}:
// wave patch pw = 1<<s wide, ph = 64>>s tall.
__global__ void setup_coef(const float* __restrict__ theta,
                           const float* __restrict__ probs,
                           float* __restrict__ coef) {
    int t = threadIdx.x;
    if (t >= T) return;
    float sum = 0.f;
    for (int i = 0; i < T; ++i) sum += probs[i];
    float p = probs[t] / sum;
    const float* th = theta + 6 * t;
    float a = th[0], b = th[1], c = th[2];
    float d = th[3], e = th[4], f = th[5];
    float Cx = a * ((1.0f - (float)W) * 0.5f)
             + b * ((1.0f - (float)H) * 0.5f)
             + (c + 1.0f) * ((float)W * 0.5f) - 0.5f;
    float Cy = d * ((1.0f - (float)W) * 0.5f)
             + e * ((1.0f - (float)H) * 0.5f)
             + (f + 1.0f) * ((float)H * 0.5f) - 0.5f;
    // pick shape minimizing modeled distinct-line count of a 64-lane gather
    float ax = fabsf(a), bx = fabsf(b), ay = fabsf(d), by = fabsf(e);
    int best_s = 3; float best = 3.4e38f;
    for (int s = 2; s <= 4; ++s) {
        float pw = (float)(1 << s), ph = (float)(64 >> s);
        float rows = pw * ay + ph * by + 2.f;
        float rowbytes = (pw * ax + ph * bx + 2.f) * 8.f + 8.f;
        float score = rows * (1.f + rowbytes * (1.f / 64.f));
        if (score < best) { best = score; best_s = s; }
    }
    float* o = coef + 8 * t;
    o[0] = p;  o[1] = a;  o[2] = b;  o[3] = Cx + 2.0f;
    o[4] = d;  o[5] = e;  o[6] = Cy + 2.0f;
    o[7] = __int_as_float(best_s);
}

// One thread per 16x16 tile: conservative bbox hit test (exact skip); compact
// active transforms into THREE shape buckets (s=2,3,4), each zero-padded to a
// multiple of 4 (dummies: all-zero -> p=0, off=0 -> exact no-op).
// Tile table (stride TSTR floats): hdr[0..2]=n2p,n3p,n4p (int bits), entries
// from +8: n2p rows, then n3p, then n4p (8 floats each).
__global__ __launch_bounds__(256) void setup_tiles(const float* __restrict__ coef,
                                                   float* __restrict__ tbl) {
    int tile = blockIdx.x * 256 + threadIdx.x;
    if (tile >= NTILES) return;
    int tx = tile & (TILES_X - 1), ty = tile >> 6;
    float w0 = (float)(tx * 16), w1 = w0 + 15.f;
    float h0 = (float)(ty * 16), h1 = h0 + 15.f;
    int list[3][T]; int n[3] = {0, 0, 0};
    for (int t = 0; t < T; ++t) {
        const float* c = coef + t * 8;
        float Ax = c[1], Bx = c[2], Cx = c[3];
        float Ay = c[4], By = c[5], Cy = c[6];
        float xmin = Cx + (Ax >= 0.f ? Ax * w0 : Ax * w1) + (Bx >= 0.f ? Bx * h0 : Bx * h1);
        float xmax = Cx + (Ax >= 0.f ? Ax * w1 : Ax * w0) + (Bx >= 0.f ? Bx * h1 : Bx * h0);
        float ymin = Cy + (Ay >= 0.f ? Ay * w0 : Ay * w1) + (By >= 0.f ? By * h0 : By * h1);
        float ymax = Cy + (Ay >= 0.f ? Ay * w1 : Ay * w0) + (By >= 0.f ? By * h1 : By * h0);
        bool hit = !(xmax <= 1.f || xmin >= (float)(W + 2) ||
                     ymax <= 1.f || ymin >= (float)(H + 2));
        if (hit) {
            int s = __float_as_int(c[7]);          // 2..4
            list[s - 2][n[s - 2]++] = t;
        }
    }
    float* o = tbl + tile * TSTR;
    int pos = 8;
    int np[3];
    for (int b = 0; b < 3; ++b) {
        int nb = n[b];
        int nbp = (nb + 3) & ~3;
        np[b] = nbp;
        for (int i = 0; i < nb; ++i) {
            const float* c = coef + list[b][i] * 8;
            for (int j = 0; j < 8; ++j) o[pos + j] = c[j];
            pos += 8;
        }
        for (int i = nb; i < nbp; ++i) {           // exact no-op dummies
            for (int j = 0; j < 8; ++j) o[pos + j] = 0.f;
            pos += 8;
        }
    }
    o[0] = __int_as_float(np[0]);
    o[1] = __int_as_float(np[1]);
    o[2] = __int_as_float(np[2]);
    for (int j = 3; j < 8; ++j) o[j] = 0.f;
}

// Build initial pair buffer from canvas0: pixel (h,w) value v contributes
// buf2[h+2][w+2].x = v and buf2[h+1][w+2].y = v. Borders stay memset-zero.
__global__ __launch_bounds__(256) void copy_in(const float* __restrict__ src,
                                               float* __restrict__ dstf) {
    int i = blockIdx.x * 256 + threadIdx.x;   // i in [0, H*W)
    int h = i >> 10, w = i & 1023;
    float v = src[i];
    int c = w + 2;
    dstf[(((h + 2) * P2) + c) * 2 + 0] = v;
    dstf[(((h + 1) * P2) + c) * 2 + 1] = v;
}

// K transforms per group: coefs via uniform scalar loads; one f4 gather per
// transform fetches all 4 corners (v00,v10,v01,v11). Fully-dead wave skips
// the gather (scalar branch); dead lanes collapse to offset 0.
template <int K>
__device__ __forceinline__ void ifs_body(const float* __restrict__ tc, int g,
                                         const f2* __restrict__ gb,
                                         float wf, float hf, float& acc) {
    float fx[K], fy[K], pp[K];
    int off[K];
    unsigned long long lv[K];
#pragma unroll
    for (int k = 0; k < K; ++k) {
        const float* c = tc + (g + k) * 8;          // uniform -> s_load
        float p = c[0], Ax = c[1], Bx = c[2], Cx = c[3];
        float Ay = c[4], By = c[5], Cy = c[6];
        float xb = fmaf(Ax, wf, fmaf(Bx, hf, Cx));
        float yb = fmaf(Ay, wf, fmaf(By, hf, Cy));
        // live <=> contribution can be nonzero
        bool live = (xb > 1.f) & (xb < 1026.f) & (yb > 1.f) & (yb < 1026.f);
        lv[k] = __ballot(live);
        float xc = fminf(fmaxf(xb, 0.f), 1037.f);   // v_med3
        float yc = fminf(fmaxf(yb, 0.f), 1026.f);
        float xi = floorf(xc), yi = floorf(yc);
        fx[k] = xc - xi;
        fy[k] = yc - yi;
        int o = (int)fmaf(yi, (float)P2, xi);       // exact (< 2^24)
        off[k] = live ? o : 0;                      // dead lane -> guard row 0
        pp[k] = p;
    }
    f4 q[K];
#pragma unroll
    for (int k = 0; k < K; ++k) {                   // live gathers in flight
        if (lv[k]) q[k] = *(const f4*)(gb + off[k]);
        else       q[k] = f4{0.f, 0.f, 0.f, 0.f};   // all corners zero
    }
#pragma unroll
    for (int k = 0; k < K; ++k) {
        // q = (v00, v10, v01, v11)
        float top = fmaf(fx[k], q[k].z - q[k].x, q[k].x);
        float bot = fmaf(fx[k], q[k].w - q[k].y, q[k].y);
        acc = fmaf(pp[k], fmaf(fy[k], bot - top, top), acc);
    }
}

// One shape group: fixed thread->pixel map, register accumulate, LDS flush.
template <int S>
__device__ __forceinline__ void run_shape(const float* __restrict__ tc, int n,
                                          const f2* __restrict__ gb,
                                          int tbw, int tbh, int lane, int wv,
                                          float* __restrict__ lacc) {
    if (n == 0) return;                             // block-uniform branch
    constexpr int pw = 1 << S;
    int dw = lane & (pw - 1), dh = lane >> S;
    int sw = wv << S;
    int ow = sw & 15, oh = (sw >> 4) << (6 - S);    // 4 waves tile 16x16
    int px = ow + dw, py = oh + dh;
    float wf = (float)(tbw + px), hf = (float)(tbh + py);

    float accR = 0.f;
    int g = 0;
    for (; g + 8 <= n; g += 8) ifs_body<8>(tc, g, gb, wf, hf, accR);
    if (g < n)                 ifs_body<4>(tc, g, gb, wf, hf, accR);

    __syncthreads();                                // order flushes; uniform
    lacc[(py << 4) | px] += accR;                   // unique owner -> no race
}

__global__ __launch_bounds__(256) void ifs_iter(const float* __restrict__ inf,
                                                float* __restrict__ dstf,
                                                const float* __restrict__ tbl,
                                                const float* __restrict__ base,
                                                int last) {
    __shared__ float lacc[256];

    int tile = blockIdx.y * TILES_X + blockIdx.x;
    const float* hdr = tbl + tile * TSTR;           // uniform
    int n2 = __float_as_int(hdr[0]);
    int n3 = __float_as_int(hdr[1]);
    int n4 = __float_as_int(hdr[2]);
    const float* tc = hdr + 8;

    int lid = threadIdx.x;
    int lane = lid & 63, wv = lid >> 6;
    int tbw = blockIdx.x << 4, tbh = blockIdx.y << 4;
    const f2* gb = (const f2*)inf;

    lacc[lid] = 0.f;                                // no sync needed: first
                                                    // flush syncs before RMW
    run_shape<2>(tc, n2, gb, tbw, tbh, lane, wv, lacc);
    run_shape<3>(tc + n2 * 8, n3, gb, tbw, tbh, lane, wv, lacc);
    run_shape<4>(tc + (n2 + n3) * 8, n4, gb, tbw, tbh, lane, wv, lacc);
    __syncthreads();

    float v = lacc[lid];
    int w = tbw + (lid & 15), h = tbh + (lid >> 4);
    if (last) {
        dstf[(h << 10) + w] = v + base[0];
    } else {
        int c = w + 2;
        dstf[(((h + 2) * P2) + c) * 2 + 0] = v;
        dstf[(((h + 1) * P2) + c) * 2 + 1] = v;
    }
}

extern "C" void kernel_launch(void* const* d_in, const int* in_sizes, int n_in,
                              void* d_out, int out_size, void* d_ws, size_t ws_size,
                              hipStream_t stream) {
    const float* canvas0 = (const float*)d_in[0];
    const float* theta   = (const float*)d_in[1];
    const float* probs   = (const float*)d_in[2];
    const float* base    = (const float*)d_in[3];

    float* raw   = (float*)d_ws;
    float* bufAf = raw;
    float* bufBf = raw + ALLOC2F;
    float* coef  = raw + 2 * ALLOC2F;
    float* tbl   = coef + T * 8;

    // zero both pair buffers: borders, gutters, guards (and kills poison)
    hipMemsetAsync(raw, 0, (size_t)2 * ALLOC2F * sizeof(float), stream);

    setup_coef<<<1, 64, 0, stream>>>(theta, probs, coef);
    setup_tiles<<<(NTILES + 255) / 256, 256, 0, stream>>>(coef, tbl);
    copy_in<<<(H * W) / 256, 256, 0, stream>>>(canvas0, bufAf);

    dim3 block(256);
    dim3 grid(TILES_X, TILES_Y);

    const float* cur = bufAf;
    for (int i = 0; i < ITERS; ++i) {
        bool last = (i == ITERS - 1);
        float* dst = last ? (float*)d_out : ((i & 1) ? bufAf : bufBf);
        ifs_iter<<<grid, block, 0, stream>>>(cur, dst, tbl, base,
                                             last ? 1 : 0);
        cur = dst;
    }
}

// Round 11
// 373.599 us; speedup vs baseline: 8.8497x; 1.2928x over previous
//
#include <hip/hip_runtime.h>

// H=W=1024, T=16, 20 iterations.
//
// R14 = R11 verbatim (best verified: 374.3 us). Final configuration.
// (Rounds 9/10 failed in the harness/broker, not the kernel; resubmitting.)
//
// R11 = R8 (pair-buffer, single-f4-gather, 256-thr blocks, no syncs/swizzle)
//       + EXACT zero-contribution skipping:
//   - a sample contributes exactly 0 iff xb<=1 || xb>=1026 || yb<=1 || yb>=1026
//     (all 4 corners then lie in zero border/guard cells; fmaf(p,0,acc)==acc
//     bit-exactly, and acc is a sum of nonnegative products so never -0).
//   - wave-level: if no lane is live for transform k, skip its gather entirely
//     (scalar branch on __ballot).
//   - lane-level: dead lanes in live waves collapse their offset to 0 (guard
//     row, all-zero cells) -> one broadcast line instead of scattered rail
//     probes.
//
// Intermediates live in two VERTICAL-PAIR buffers:
//   buf2[r][c] = ( pad[r-1][c-1], pad[r][c-1] )   (float2, 8 B)
// where pad[y][x] is the zero-bordered padded canvas (pixel (h,w) at
// pad[h+1][w+1]). The 4 bilinear corners of a sample live in TWO ADJACENT f2
// elements -> ONE 16B dwordx4 gather per (pixel, transform). Guards/gutters
// are memset-zero once and never written, so clamped OOB samples read exact
// 0.0 (zeros padding exact, no per-lane cmp/cndmask in the value path).
constexpr int W = 1024;
constexpr int H = 1024;
constexpr int T = 16;
constexpr int ITERS = 20;
constexpr int P2 = 1040;                 // f2 elements per row (8320 B rows)
constexpr int ROWS2 = 1027;              // rows 0..1026 readable
constexpr int ALLOC2F = ROWS2 * P2 * 2;  // floats per pair-buffer allocation
constexpr int TILES_X = W / 16;          // 64
constexpr int TILES_Y = H / 16;          // 64
constexpr int NTILES = TILES_X * TILES_Y;

typedef float f2 __attribute__((ext_vector_type(2), aligned(8)));
typedef float f4 __attribute__((ext_vector_type(4), aligned(8)));  // 8B-aligned ok

// coef per transform t: {p, Ax, Bx, Cxb, Ay, By, Cyb, 0}; Cxb/Cyb include the
// +1 pad shift AND +1 clamp bias.
__global__ void setup_coef(const float* __restrict__ theta,
                           const float* __restrict__ probs,
                           float* __restrict__ coef) {
    int t = threadIdx.x;
    if (t >= T) return;
    float sum = 0.f;
    for (int i = 0; i < T; ++i) sum += probs[i];
    float p = probs[t] / sum;
    const float* th = theta + 6 * t;
    float a = th[0], b = th[1], c = th[2];
    float d = th[3], e = th[4], f = th[5];
    float Cx = a * ((1.0f - (float)W) * 0.5f)
             + b * ((1.0f - (float)H) * 0.5f)
             + (c + 1.0f) * ((float)W * 0.5f) - 0.5f;
    float Cy = d * ((1.0f - (float)W) * 0.5f)
             + e * ((1.0f - (float)H) * 0.5f)
             + (f + 1.0f) * ((float)H * 0.5f) - 0.5f;
    float* o = coef + 8 * t;
    o[0] = p;  o[1] = a;  o[2] = b;  o[3] = Cx + 2.0f;
    o[4] = d;  o[5] = e;  o[6] = Cy + 2.0f; o[7] = 0.f;
}

// One thread per 16x16 tile: conservative bbox hit test (exact skip), compact
// the active transforms' 8-float coef rows, zero-pad count to multiple of 4
// (dummy rows are all-zero -> p=0, off=0 -> exact no-op).
__global__ __launch_bounds__(256) void setup_tiles(const float* __restrict__ coef,
                                                   float* __restrict__ tbl,
                                                   int* __restrict__ tcnt) {
    int tile = blockIdx.x * 256 + threadIdx.x;
    if (tile >= NTILES) return;
    int tx = tile & (TILES_X - 1), ty = tile >> 6;
    float w0 = (float)(tx * 16), w1 = w0 + 15.f;
    float h0 = (float)(ty * 16), h1 = h0 + 15.f;
    float* o = tbl + tile * 128;
    int n = 0;
    for (int t = 0; t < T; ++t) {
        const float* c = coef + t * 8;
        float Ax = c[1], Bx = c[2], Cx = c[3];
        float Ay = c[4], By = c[5], Cy = c[6];
        float xmin = Cx + (Ax >= 0.f ? Ax * w0 : Ax * w1) + (Bx >= 0.f ? Bx * h0 : Bx * h1);
        float xmax = Cx + (Ax >= 0.f ? Ax * w1 : Ax * w0) + (Bx >= 0.f ? Bx * h1 : Bx * h0);
        float ymin = Cy + (Ay >= 0.f ? Ay * w0 : Ay * w1) + (By >= 0.f ? By * h0 : By * h1);
        float ymax = Cy + (Ay >= 0.f ? Ay * w1 : Ay * w0) + (By >= 0.f ? By * h1 : By * h0);
        bool hit = !(xmax <= 1.f || xmin >= (float)(W + 2) ||
                     ymax <= 1.f || ymin >= (float)(H + 2));
        if (hit) {
            for (int j = 0; j < 8; ++j) o[n * 8 + j] = c[j];
            ++n;
        }
    }
    tcnt[tile] = n;
    int np = (n + 3) & ~3;
    for (int s = n; s < np; ++s)
        for (int j = 0; j < 8; ++j) o[s * 8 + j] = 0.f;
}

// Build initial pair buffer from canvas0: pixel (h,w) value v contributes
// buf2[h+2][w+2].x = v and buf2[h+1][w+2].y = v. Borders stay memset-zero.
__global__ __launch_bounds__(256) void copy_in(const float* __restrict__ src,
                                               float* __restrict__ dstf) {
    int i = blockIdx.x * 256 + threadIdx.x;   // i in [0, H*W)
    int h = i >> 10, w = i & 1023;
    float v = src[i];
    int c = w + 2;
    dstf[(((h + 2) * P2) + c) * 2 + 0] = v;
    dstf[(((h + 1) * P2) + c) * 2 + 1] = v;
}

// K transforms per group: coefs via uniform scalar loads; one f4 gather per
// transform fetches all 4 corners (v00,v10,v01,v11). Fully-dead wave skips
// the gather (scalar branch); dead lanes collapse to offset 0.
template <int K>
__device__ __forceinline__ void ifs_body(const float* __restrict__ tc, int g,
                                         const f2* __restrict__ gb,
                                         float wf, float hf, float& acc) {
    float fx[K], fy[K], pp[K];
    int off[K];
    unsigned long long lv[K];
#pragma unroll
    for (int k = 0; k < K; ++k) {
        const float* c = tc + (g + k) * 8;          // uniform -> s_load
        float p = c[0], Ax = c[1], Bx = c[2], Cx = c[3];
        float Ay = c[4], By = c[5], Cy = c[6];
        float xb = fmaf(Ax, wf, fmaf(Bx, hf, Cx));
        float yb = fmaf(Ay, wf, fmaf(By, hf, Cy));
        // live <=> contribution can be nonzero
        bool live = (xb > 1.f) & (xb < 1026.f) & (yb > 1.f) & (yb < 1026.f);
        lv[k] = __ballot(live);
        float xc = fminf(fmaxf(xb, 0.f), 1037.f);   // v_med3
        float yc = fminf(fmaxf(yb, 0.f), 1026.f);
        float xi = floorf(xc), yi = floorf(yc);
        fx[k] = xc - xi;
        fy[k] = yc - yi;
        int o = (int)fmaf(yi, (float)P2, xi);       // exact (< 2^24)
        off[k] = live ? o : 0;                      // dead lane -> guard row 0
        pp[k] = p;
    }
    f4 q[K];
#pragma unroll
    for (int k = 0; k < K; ++k) {                   // live gathers in flight
        if (lv[k]) q[k] = *(const f4*)(gb + off[k]);
        else       q[k] = f4{0.f, 0.f, 0.f, 0.f};   // all corners zero
    }
#pragma unroll
    for (int k = 0; k < K; ++k) {
        // q = (v00, v10, v01, v11)
        float top = fmaf(fx[k], q[k].z - q[k].x, q[k].x);
        float bot = fmaf(fx[k], q[k].w - q[k].y, q[k].y);
        acc = fmaf(pp[k], fmaf(fy[k], bot - top, top), acc);
    }
}

__global__ __launch_bounds__(256) void ifs_iter(const float* __restrict__ inf,
                                                float* __restrict__ dstf,
                                                const float* __restrict__ tbl,
                                                const int* __restrict__ tcnt,
                                                const float* __restrict__ base,
                                                int last) {
    int tile = blockIdx.y * TILES_X + blockIdx.x;
    const float* tc = tbl + tile * 128;             // uniform
    int np = (tcnt[tile] + 3) & ~3;                 // uniform trip count

    // 8x8-per-wave mapping; 4 waves tile a 16x16 pixel block.
    int lid = threadIdx.x;
    int lane = lid & 63, wv = lid >> 6;
    int w = (blockIdx.x << 4) + ((wv & 1) << 3) + (lane & 7);
    int h = (blockIdx.y << 4) + ((wv >> 1) << 3) + (lane >> 3);
    float wf = (float)w, hf = (float)h;
    const f2* gb = (const f2*)inf;

    float acc = 0.f;
    int g = 0;
    for (; g + 8 <= np; g += 8) ifs_body<8>(tc, g, gb, wf, hf, acc);
    if (g < np)                 ifs_body<4>(tc, g, gb, wf, hf, acc);

    if (last) {
        dstf[(h << 10) + w] = acc + base[0];
    } else {
        int c = w + 2;
        dstf[(((h + 2) * P2) + c) * 2 + 0] = acc;
        dstf[(((h + 1) * P2) + c) * 2 + 1] = acc;
    }
}

extern "C" void kernel_launch(void* const* d_in, const int* in_sizes, int n_in,
                              void* d_out, int out_size, void* d_ws, size_t ws_size,
                              hipStream_t stream) {
    const float* canvas0 = (const float*)d_in[0];
    const float* theta   = (const float*)d_in[1];
    const float* probs   = (const float*)d_in[2];
    const float* base    = (const float*)d_in[3];

    float* raw   = (float*)d_ws;
    float* bufAf = raw;
    float* bufBf = raw + ALLOC2F;
    float* coef  = raw + 2 * ALLOC2F;
    float* tbl   = coef + T * 8;
    int*   tcnt  = (int*)(tbl + NTILES * 128);

    // zero both pair buffers: borders, gutters, guards (and kills poison)
    hipMemsetAsync(raw, 0, (size_t)2 * ALLOC2F * sizeof(float), stream);

    setup_coef<<<1, 64, 0, stream>>>(theta, probs, coef);
    setup_tiles<<<(NTILES + 255) / 256, 256, 0, stream>>>(coef, tbl, tcnt);
    copy_in<<<(H * W) / 256, 256, 0, stream>>>(canvas0, bufAf);

    dim3 block(256);
    dim3 grid(TILES_X, TILES_Y);

    const float* cur = bufAf;
    for (int i = 0; i < ITERS; ++i) {
        bool last = (i == ITERS - 1);
        float* dst = last ? (float*)d_out : ((i & 1) ? bufAf : bufBf);
        ifs_iter<<<grid, block, 0, stream>>>(cur, dst, tbl, tcnt, base,
                                             last ? 1 : 0);
        cur = dst;
    }
}